// Round 1
// baseline (270.565 us; speedup 1.0000x reference)
//
#include <hip/hip_runtime.h>

typedef __attribute__((ext_vector_type(8))) short short8;
typedef __attribute__((ext_vector_type(4))) float f32x4;

#define MFMA16(a, b, c) __builtin_amdgcn_mfma_f32_16x16x32_bf16(a, b, c, 0, 0, 0)

__device__ __forceinline__ ushort bf16_rne(float f) {
  uint u = __float_as_uint(f);
  u += 0x7FFFu + ((u >> 16) & 1u);
  return (ushort)(u >> 16);
}
__device__ __forceinline__ float bf16_hi_f(ushort h) {
  return __uint_as_float(((uint)h) << 16);
}

// ---------------- weight split (fp32 -> bf16 hi + bf16 lo, padded) ----------------
__global__ void split_w_kernel(const float* __restrict__ W, ushort* __restrict__ hi,
                               ushort* __restrict__ lo, int Nr, int K, int Npad, int Kp) {
  int i = blockIdx.x * 256 + threadIdx.x;
  if (i >= Npad * Kp) return;
  int r = i / Kp, k = i - r * Kp;
  float v = (r < Nr && k < K) ? W[(size_t)r * K + k] : 0.f;
  ushort h = bf16_rne(v);
  ushort l = bf16_rne(v - bf16_hi_f(h));
  hi[i] = h;
  lo[i] = l;
}

// ---------------- NT GEMM: C[M][ldc] = A[M][K] * B[N][K]^T ----------------
// A: fp32 (split on the fly, 3 passes) if SPLIT_A, else bf16 (2 passes).
// B: pre-split bf16 hi/lo, row-major [N][Bst], Bst padded to multiple of 64.
// Tile: 128(M) x BN(N) x 64(K). 4 waves, each owns 64 x (BN==128?64:16).
template <int BN, bool SPLIT_A>
__global__ __launch_bounds__(256) void gemm_nt(const void* __restrict__ Aptr, int Ast,
                                               const ushort* __restrict__ Bh,
                                               const ushort* __restrict__ Bl, int Bst,
                                               float* __restrict__ C, int ldc, int ksteps) {
  __shared__ ushort sAh[128 * 64];
  __shared__ ushort sAl[SPLIT_A ? 128 * 64 : 8];
  __shared__ ushort sBh[BN * 64];
  __shared__ ushort sBl[BN * 64];

  const int tid = threadIdx.x;
  const int m0 = blockIdx.x * 128;
  const int n0 = blockIdx.y * BN;
  const int tr = tid >> 3;  // 0..31
  const int tg = tid & 7;   // k-group 0..7
  const int lane = tid & 63;
  const int wid = tid >> 6;
  const int wr = wid >> 1;
  const int wc = wid & 1;
  constexpr int MF = 4;
  constexpr int NF = BN / 32;
  constexpr int WCN = (BN == 128) ? 64 : 16;

  f32x4 acc[MF][NF];
#pragma unroll
  for (int i = 0; i < MF; ++i)
#pragma unroll
    for (int j = 0; j < NF; ++j) acc[i][j] = f32x4{0.f, 0.f, 0.f, 0.f};

  for (int ks = 0; ks < ksteps; ++ks) {
    const int kc = ks * 64 + tg * 8;
    // ---- stage A tile [128][64] ----
    if (SPLIT_A) {
      const float* Af = (const float*)Aptr;
#pragma unroll
      for (int p = 0; p < 4; ++p) {
        int r = p * 32 + tr;
        const float* ap = Af + (size_t)(m0 + r) * Ast + kc;
        float v[8];
#pragma unroll
        for (int h4 = 0; h4 < 2; ++h4) {
          if (kc + h4 * 4 + 3 < Ast) {  // Ast is the true K for fp32 A
            const float4 f = *(const float4*)(ap + h4 * 4);
            v[h4 * 4 + 0] = f.x; v[h4 * 4 + 1] = f.y;
            v[h4 * 4 + 2] = f.z; v[h4 * 4 + 3] = f.w;
          } else {
            v[h4 * 4 + 0] = 0.f; v[h4 * 4 + 1] = 0.f;
            v[h4 * 4 + 2] = 0.f; v[h4 * 4 + 3] = 0.f;
          }
        }
        union { ushort u[8]; uint4 q; } ph, pl;
#pragma unroll
        for (int j = 0; j < 8; ++j) {
          ushort h = bf16_rne(v[j]);
          ph.u[j] = h;
          pl.u[j] = bf16_rne(v[j] - bf16_hi_f(h));
        }
        int off = r * 64 + ((tg ^ (r & 7)) << 3);  // XOR-swizzled k-group
        *(uint4*)&sAh[off] = ph.q;
        *(uint4*)&sAl[off] = pl.q;
      }
    } else {
      const ushort* Au = (const ushort*)Aptr;
#pragma unroll
      for (int p = 0; p < 4; ++p) {
        int r = p * 32 + tr;
        uint4 q = *(const uint4*)(Au + (size_t)(m0 + r) * Ast + kc);
        *(uint4*)&sAh[r * 64 + ((tg ^ (r & 7)) << 3)] = q;
      }
    }
    // ---- stage B tile [BN][64] (already bf16 hi/lo, padded) ----
#pragma unroll
    for (int p = 0; p < BN / 32; ++p) {
      int r = p * 32 + tr;
      size_t go = (size_t)(n0 + r) * Bst + kc;
      int off = r * 64 + ((tg ^ (r & 7)) << 3);
      *(uint4*)&sBh[off] = *(const uint4*)(Bh + go);
      *(uint4*)&sBl[off] = *(const uint4*)(Bl + go);
    }
    __syncthreads();

    // ---- compute: 2 k-substeps of 32 ----
#pragma unroll
    for (int ku = 0; ku < 2; ++ku) {
      const int g0 = ku * 4 + (lane >> 4);
      short8 ah[MF], al[MF];
#pragma unroll
      for (int i = 0; i < MF; ++i) {
        int r = wr * 64 + i * 16 + (lane & 15);
        int off = r * 64 + ((g0 ^ (r & 7)) << 3);
        ah[i] = *(const short8*)&sAh[off];
        if (SPLIT_A) al[i] = *(const short8*)&sAl[off];
      }
      short8 bh[NF], bl[NF];
#pragma unroll
      for (int j = 0; j < NF; ++j) {
        int r = wc * WCN + j * 16 + (lane & 15);
        int off = r * 64 + ((g0 ^ (r & 7)) << 3);
        bh[j] = *(const short8*)&sBh[off];
        bl[j] = *(const short8*)&sBl[off];
      }
#pragma unroll
      for (int i = 0; i < MF; ++i)
#pragma unroll
        for (int j = 0; j < NF; ++j) {
          acc[i][j] = MFMA16(ah[i], bh[j], acc[i][j]);
          if (SPLIT_A) {
            acc[i][j] = MFMA16(al[i], bh[j], acc[i][j]);
            acc[i][j] = MFMA16(ah[i], bl[j], acc[i][j]);
          } else {
            acc[i][j] = MFMA16(ah[i], bl[j], acc[i][j]);
          }
        }
    }
    __syncthreads();
  }

  // ---- epilogue: C/D layout col=lane&15, row=(lane>>4)*4+reg ----
#pragma unroll
  for (int i = 0; i < MF; ++i) {
    int rbase = m0 + wr * 64 + i * 16 + ((lane >> 4) << 2);
#pragma unroll
    for (int j = 0; j < NF; ++j) {
      int col = n0 + wc * WCN + j * 16 + (lane & 15);
      if (col < ldc) {
#pragma unroll
        for (int rg = 0; rg < 4; ++rg)
          C[(size_t)(rbase + rg) * ldc + col] = acc[i][j][rg];
      }
    }
  }
}

// ---------------- LIF scan: one block per batch element, thread = neuron ----------------
__global__ void lif_kernel(const float* __restrict__ cur, const float* __restrict__ bias,
                           ushort* __restrict__ spk, const float* __restrict__ beta_p,
                           const float* __restrict__ thr_p) {
  const int N = blockDim.x;
  const int n = threadIdx.x;
  const int b = blockIdx.x;
  const float beta = fminf(fmaxf(beta_p[0], 0.f), 1.f);
  const float thr = thr_p[0];
  const float bi = bias[n];
  const float* cp = cur + (size_t)b * 500 * N + n;
  ushort* sp = spk + (size_t)b * 500 * N + n;
  float m = 0.f;
  for (int t0 = 0; t0 < 500; t0 += 20) {
    float c[20];
#pragma unroll
    for (int u = 0; u < 20; ++u) c[u] = cp[(size_t)(t0 + u) * N];
    ushort s[20];
#pragma unroll
    for (int u = 0; u < 20; ++u) {
      float r = (m > thr) ? thr : 0.f;  // reset uses previous mem
      m = beta * m + (c[u] + bi) - r;
      s[u] = (m > thr) ? (ushort)0x3F80 : (ushort)0;  // bf16 1.0 / 0.0
    }
#pragma unroll
    for (int u = 0; u < 20; ++u) sp[(size_t)(t0 + u) * N] = s[u];
  }
}

// ---------------- LIF3 + time-mean ----------------
__global__ void lif3_mean_kernel(const float* __restrict__ cur3, const float* __restrict__ b3,
                                 const float* __restrict__ beta_p,
                                 const float* __restrict__ thr_p, float* __restrict__ out) {
  const int n = threadIdx.x;  // 64 threads, 20 active
  const int b = blockIdx.x;
  const float beta = fminf(fmaxf(beta_p[0], 0.f), 1.f);
  const float thr = thr_p[0];
  const float bi = (n < 20) ? b3[n] : 0.f;
  const float* cp = cur3 + (size_t)b * 500 * 20 + (n < 20 ? n : 0);
  float m = 0.f, acc = 0.f;
  for (int t0 = 0; t0 < 500; t0 += 20) {
    float c[20];
#pragma unroll
    for (int u = 0; u < 20; ++u) c[u] = cp[(size_t)(t0 + u) * 20];
#pragma unroll
    for (int u = 0; u < 20; ++u) {
      float r = (m > thr) ? thr : 0.f;
      m = beta * m + (c[u] + bi) - r;
      acc += (m > thr) ? 1.f : 0.f;
    }
  }
  if (n < 20) out[(size_t)b * 20 + n] = acc * (1.f / 500.f);
}

extern "C" void kernel_launch(void* const* d_in, const int* in_sizes, int n_in, void* d_out,
                              int out_size, void* d_ws, size_t ws_size, hipStream_t stream) {
  const float* x = (const float*)d_in[0];
  const float* W1 = (const float*)d_in[1];
  const float* b1 = (const float*)d_in[2];
  const float* W2 = (const float*)d_in[3];
  const float* b2 = (const float*)d_in[4];
  const float* W3 = (const float*)d_in[5];
  const float* b3 = (const float*)d_in[6];
  const float* beta1 = (const float*)d_in[7];
  const float* beta2 = (const float*)d_in[8];
  const float* beta3 = (const float*)d_in[9];
  const float* thr1 = (const float*)d_in[10];
  const float* thr2 = (const float*)d_in[11];
  const float* thr3 = (const float*)d_in[12];
  float* out = (float*)d_out;

  const int M = 128000;  // B*T = 256*500
  char* ws = (char*)d_ws;
  // region 0: cur2 [M][256] f32 (131.072 MB); cur1 [M][128] shares its front half
  float* cur2 = (float*)ws;
  float* cur1 = cur2;
  size_t off = (size_t)M * 256 * 4;
  // region 1: s1 [M][128] bf16 (32.768 MB); cur3 [M][20] f32 overlays it after GEMM2
  ushort* s1 = (ushort*)(ws + off);
  float* cur3 = (float*)(ws + off);
  off += (size_t)M * 128 * 2;
  // region 2: s2 [M][256] bf16 (65.536 MB)
  ushort* s2 = (ushort*)(ws + off);
  off += (size_t)M * 256 * 2;
  // weights (split, padded)
  ushort* w1h = (ushort*)(ws + off); off += 128 * 704 * 2;
  ushort* w1l = (ushort*)(ws + off); off += 128 * 704 * 2;
  ushort* w2h = (ushort*)(ws + off); off += 256 * 128 * 2;
  ushort* w2l = (ushort*)(ws + off); off += 256 * 128 * 2;
  ushort* w3h = (ushort*)(ws + off); off += 32 * 256 * 2;
  ushort* w3l = (ushort*)(ws + off); off += 32 * 256 * 2;

  split_w_kernel<<<(128 * 704 + 255) / 256, 256, 0, stream>>>(W1, w1h, w1l, 128, 700, 128, 704);
  split_w_kernel<<<(256 * 128 + 255) / 256, 256, 0, stream>>>(W2, w2h, w2l, 256, 128, 256, 128);
  split_w_kernel<<<(32 * 256 + 255) / 256, 256, 0, stream>>>(W3, w3h, w3l, 20, 256, 32, 256);

  // layer 1: cur1 = x @ W1^T  (fp32 A split on the fly, 3 MFMA passes)
  gemm_nt<128, true><<<dim3(M / 128, 1), 256, 0, stream>>>(x, 700, w1h, w1l, 704, cur1, 128, 11);
  lif_kernel<<<256, 128, 0, stream>>>(cur1, b1, s1, beta1, thr1);
  // layer 2: cur2 = s1 @ W2^T  (bf16 A exact, 2 passes)
  gemm_nt<128, false><<<dim3(M / 128, 2), 256, 0, stream>>>(s1, 128, w2h, w2l, 128, cur2, 256, 2);
  lif_kernel<<<256, 256, 0, stream>>>(cur2, b2, s2, beta2, thr2);
  // layer 3: cur3 = s2 @ W3^T  (N=20 padded to 32)
  gemm_nt<32, false><<<dim3(M / 128, 1), 256, 0, stream>>>(s2, 256, w3h, w3l, 256, cur3, 20, 4);
  lif3_mean_kernel<<<256, 64, 0, stream>>>(cur3, b3, beta3, thr3, out);
}

// Round 2
// 256.247 us; speedup vs baseline: 1.0559x; 1.0559x over previous
//
#include <hip/hip_runtime.h>

typedef __attribute__((ext_vector_type(8))) short short8;
typedef __attribute__((ext_vector_type(4))) float f32x4;

#define MFMA16(a, b, c) __builtin_amdgcn_mfma_f32_16x16x32_bf16(a, b, c, 0, 0, 0)

__device__ __forceinline__ ushort bf16_rne(float f) {
  uint u = __float_as_uint(f);
  u += 0x7FFFu + ((u >> 16) & 1u);
  return (ushort)(u >> 16);
}

// ---------------- weight split (fp32 -> bf16 hi + bf16 lo, padded) ----------------
__global__ void split_w_kernel(const float* __restrict__ W, ushort* __restrict__ hi,
                               ushort* __restrict__ lo, int Nr, int K, int Npad, int Kp) {
  int i = blockIdx.x * 256 + threadIdx.x;
  if (i >= Npad * Kp) return;
  int r = i / Kp, k = i - r * Kp;
  float v = (r < Nr && k < K) ? W[(size_t)r * K + k] : 0.f;
  ushort h = bf16_rne(v);
  float hf = __uint_as_float(((uint)h) << 16);
  ushort l = bf16_rne(v - hf);
  hi[i] = h;
  lo[i] = l;
}

// ---------------- GEMM1: cur1[M][128] = x[M][700] @ W1^T, 3-pass split-bf16 ----------------
__device__ __forceinline__ void load_a_tile(const float* __restrict__ A, int m0, int tr, int tg,
                                            int ks, float4 pf[8]) {
#pragma unroll
  for (int p = 0; p < 4; ++p) {
    const float* ap = A + (size_t)(m0 + p * 32 + tr) * 700 + ks * 64 + tg * 8;
#pragma unroll
    for (int h = 0; h < 2; ++h) {
      float4 z;
      z.x = z.y = z.z = z.w = 0.f;
      pf[p * 2 + h] = (ks * 64 + tg * 8 + h * 4 + 3 < 700) ? *(const float4*)(ap + h * 4) : z;
    }
  }
}

__global__ __launch_bounds__(256, 2) void gemm1_kernel(const float* __restrict__ A,
                                                       const ushort* __restrict__ Bh,
                                                       const ushort* __restrict__ Bl,
                                                       float* __restrict__ C) {
  __shared__ ushort sAh[128 * 64];
  __shared__ ushort sAl[128 * 64];
  __shared__ ushort sBh[128 * 64];
  __shared__ ushort sBl[128 * 64];

  const int tid = threadIdx.x;
  const int lane = tid & 63;
  const int wid = tid >> 6;
  const int tr = tid >> 3, tg = tid & 7;
  const int wr = wid >> 1, wc = wid & 1;
  const int m0 = blockIdx.x * 128;

  f32x4 acc[4][4];
#pragma unroll
  for (int i = 0; i < 4; ++i)
#pragma unroll
    for (int j = 0; j < 4; ++j) acc[i][j] = f32x4{0.f, 0.f, 0.f, 0.f};

  float4 pf[8];
  load_a_tile(A, m0, tr, tg, 0, pf);

  for (int ks = 0; ks < 11; ++ks) {
    // ---- convert prefetched A regs -> LDS (trunc-hi split) ----
#pragma unroll
    for (int p = 0; p < 4; ++p) {
      int r = p * 32 + tr;
      union { ushort u[8]; uint4 q; } ph, pl;
#pragma unroll
      for (int hh = 0; hh < 2; ++hh)
#pragma unroll
        for (int jj = 0; jj < 4; ++jj) {
          float v = ((const float*)&pf[p * 2 + hh])[jj];
          uint u = __float_as_uint(v);
          ph.u[hh * 4 + jj] = (ushort)(u >> 16);
          float hf = __uint_as_float(u & 0xFFFF0000u);
          pl.u[hh * 4 + jj] = bf16_rne(v - hf);
        }
      int off = r * 64 + ((tg ^ (r & 7)) << 3);
      *(uint4*)&sAh[off] = ph.q;
      *(uint4*)&sAl[off] = pl.q;
    }
    // ---- stage B tile (L2-hot) ----
#pragma unroll
    for (int p = 0; p < 4; ++p) {
      int r = p * 32 + tr;
      size_t go = (size_t)r * 704 + ks * 64 + tg * 8;
      int off = r * 64 + ((tg ^ (r & 7)) << 3);
      *(uint4*)&sBh[off] = *(const uint4*)(Bh + go);
      *(uint4*)&sBl[off] = *(const uint4*)(Bl + go);
    }
    __syncthreads();
    // prefetch next A tile: loads fly during the MFMA phase
    if (ks < 10) load_a_tile(A, m0, tr, tg, ks + 1, pf);

#pragma unroll
    for (int ku = 0; ku < 2; ++ku) {
      const int g0 = ku * 4 + (lane >> 4);
      short8 ah[4], al[4];
#pragma unroll
      for (int i = 0; i < 4; ++i) {
        int r = wr * 64 + i * 16 + (lane & 15);
        int off = r * 64 + ((g0 ^ (r & 7)) << 3);
        ah[i] = *(const short8*)&sAh[off];
        al[i] = *(const short8*)&sAl[off];
      }
      short8 bh[4], bl[4];
#pragma unroll
      for (int j = 0; j < 4; ++j) {
        int r = wc * 64 + j * 16 + (lane & 15);
        int off = r * 64 + ((g0 ^ (r & 7)) << 3);
        bh[j] = *(const short8*)&sBh[off];
        bl[j] = *(const short8*)&sBl[off];
      }
#pragma unroll
      for (int i = 0; i < 4; ++i)
#pragma unroll
        for (int j = 0; j < 4; ++j) {
          acc[i][j] = MFMA16(ah[i], bh[j], acc[i][j]);
          acc[i][j] = MFMA16(al[i], bh[j], acc[i][j]);
          acc[i][j] = MFMA16(ah[i], bl[j], acc[i][j]);
        }
    }
    __syncthreads();
  }

#pragma unroll
  for (int i = 0; i < 4; ++i) {
    int rbase = m0 + wr * 64 + i * 16 + ((lane >> 4) << 2);
#pragma unroll
    for (int j = 0; j < 4; ++j) {
      int col = wc * 64 + j * 16 + (lane & 15);
#pragma unroll
      for (int rg = 0; rg < 4; ++rg)
        C[(size_t)(rbase + rg) * 128 + col] = acc[i][j][rg];
    }
  }
}

// ---------------- fused layers 2+3: one block per batch element ----------------
// LDS: s1[64][128] bf16 (16K) | sB stage 32K | c2[64][256] f32 (64K, c3 reuses front) | s2[64][256] bf16 (32K)
__global__ __launch_bounds__(512) void fused_l23_kernel(
    const float* __restrict__ cur1, const float* __restrict__ b1,
    const ushort* __restrict__ w2h, const ushort* __restrict__ w2l, const float* __restrict__ b2,
    const ushort* __restrict__ w3h, const ushort* __restrict__ w3l, const float* __restrict__ b3,
    const float* __restrict__ beta1p, const float* __restrict__ beta2p,
    const float* __restrict__ beta3p, const float* __restrict__ thr1p,
    const float* __restrict__ thr2p, const float* __restrict__ thr3p,
    float* __restrict__ out) {
  __shared__ __align__(16) char smem[147456];
  ushort* s1 = (ushort*)smem;
  ushort* sB = (ushort*)(smem + 16384);
  float* c2 = (float*)(smem + 49152);
  float* c3 = (float*)(smem + 49152);
  ushort* s2 = (ushort*)(smem + 114688);

  const int tid = threadIdx.x;
  const int lane = tid & 63;
  const int w = tid >> 6;
  const int b = blockIdx.x;
  const float be1 = fminf(fmaxf(beta1p[0], 0.f), 1.f), th1 = thr1p[0];
  const float be2 = fminf(fmaxf(beta2p[0], 0.f), 1.f), th2 = thr2p[0];
  const float be3 = fminf(fmaxf(beta3p[0], 0.f), 1.f), th3 = thr3p[0];
  const float bi1 = (tid < 128) ? b1[tid] : 0.f;
  const float bi2 = (tid < 256) ? b2[tid] : 0.f;
  const float bi3 = (tid < 20) ? b3[tid] : 0.f;

  float m1 = 0.f, m2 = 0.f, m3 = 0.f, a3 = 0.f;

  for (int cch = 0; cch < 8; ++cch) {
    const int t0 = cch * 64;

    // ---- Phase A: LIF1 (threads 0..127 = neuron n1) ----
    if (tid < 128) {
      const float* cp = cur1 + ((size_t)(b * 500) + t0) * 128 + tid;
      const int g = tid >> 3, nb = tid & 7;
#pragma unroll
      for (int h = 0; h < 2; ++h) {
        float v[32];
#pragma unroll
        for (int u = 0; u < 32; ++u) {
          int t = t0 + h * 32 + u;
          v[u] = (t < 500) ? cp[(size_t)(h * 32 + u) * 128] : 0.f;
        }
#pragma unroll
        for (int u = 0; u < 32; ++u) {
          int t = t0 + h * 32 + u;
          int row = h * 32 + u;
          ushort sp = 0;
          if (t < 500) {
            float r = (m1 > th1) ? th1 : 0.f;
            m1 = be1 * m1 + (v[u] + bi1) - r;
            sp = (m1 > th1) ? (ushort)0x3F80 : (ushort)0;
          }
          s1[row * 128 + ((g ^ (row & 7)) << 3) + nb] = sp;
        }
      }
    }
    __syncthreads();

    // ---- Phase B: GEMM2 (64x256, K=128) -> c2 ----
    f32x4 acc[4][2];
#pragma unroll
    for (int i = 0; i < 4; ++i)
#pragma unroll
      for (int j = 0; j < 2; ++j) acc[i][j] = f32x4{0.f, 0.f, 0.f, 0.f};

    for (int kst = 0; kst < 2; ++kst) {
      short8 ah[2][4];
#pragma unroll
      for (int ku = 0; ku < 2; ++ku) {
        int G = kst * 8 + ku * 4 + (lane >> 4);
#pragma unroll
        for (int i = 0; i < 4; ++i) {
          int r = i * 16 + (lane & 15);
          ah[ku][i] = *(const short8*)&s1[r * 128 + ((G ^ (r & 7)) << 3)];
        }
      }
#pragma unroll
      for (int part = 0; part < 2; ++part) {
        const ushort* Wp = part ? w2l : w2h;
#pragma unroll
        for (int p = 0; p < 4; ++p) {
          int r = p * 64 + (tid >> 3);
          *(uint4*)&sB[r * 64 + (tid & 7) * 8] =
              *(const uint4*)(Wp + r * 128 + kst * 64 + (((tid & 7) ^ (r & 7)) << 3));
        }
        __syncthreads();
#pragma unroll
        for (int ku = 0; ku < 2; ++ku) {
          int gB = ku * 4 + (lane >> 4);
#pragma unroll
          for (int j = 0; j < 2; ++j) {
            int rb = w * 32 + j * 16 + (lane & 15);
            short8 bb = *(const short8*)&sB[rb * 64 + ((gB ^ (rb & 7)) << 3)];
#pragma unroll
            for (int i = 0; i < 4; ++i) acc[i][j] = MFMA16(ah[ku][i], bb, acc[i][j]);
          }
        }
        __syncthreads();
      }
    }
    // epilogue -> c2 (bank-spreading col swizzle)
#pragma unroll
    for (int i = 0; i < 4; ++i) {
      int rbase = i * 16 + ((lane >> 4) << 2);
#pragma unroll
      for (int j = 0; j < 2; ++j) {
        int col = w * 32 + j * 16 + (lane & 15);
#pragma unroll
        for (int rg = 0; rg < 4; ++rg) {
          int row = rbase + rg;
          c2[row * 256 + (col ^ (((row >> 2) & 7) << 2))] = acc[i][j][rg];
        }
      }
    }
    __syncthreads();

    // ---- Phase C: LIF2 (threads 0..255 = neuron n2) ----
    if (tid < 256) {
      const int g = tid >> 3, nb = tid & 7;
#pragma unroll
      for (int h = 0; h < 2; ++h) {
        float v[32];
#pragma unroll
        for (int u = 0; u < 32; ++u) {
          int row = h * 32 + u;
          v[u] = c2[row * 256 + (tid ^ (((row >> 2) & 7) << 2))];
        }
#pragma unroll
        for (int u = 0; u < 32; ++u) {
          int t = t0 + h * 32 + u;
          int row = h * 32 + u;
          ushort sp = 0;
          if (t < 500) {
            float r = (m2 > th2) ? th2 : 0.f;
            m2 = be2 * m2 + (v[u] + bi2) - r;
            sp = (m2 > th2) ? (ushort)0x3F80 : (ushort)0;
          }
          s2[row * 256 + ((g ^ (row & 7)) << 3) + nb] = sp;
        }
      }
    }
    __syncthreads();

    // ---- Phase D: GEMM3 (64x32, K=256) -> c3 ----
#pragma unroll
    for (int p = 0; p < 2; ++p) {
      int r = p * 16 + (tid >> 5);
      int g = tid & 31;
      int swz = ((g ^ (r & 7)) << 3);
      *(uint4*)&sB[r * 256 + g * 8] = *(const uint4*)(w3h + r * 256 + swz);
      *(uint4*)&sB[8192 + r * 256 + g * 8] = *(const uint4*)(w3l + r * 256 + swz);
    }
    __syncthreads();
    if (w < 4) {
      const int wr = w >> 1, wc = w & 1;
      f32x4 a3c[2];
      a3c[0] = f32x4{0.f, 0.f, 0.f, 0.f};
      a3c[1] = f32x4{0.f, 0.f, 0.f, 0.f};
#pragma unroll
      for (int ku = 0; ku < 8; ++ku) {
        int G = ku * 4 + (lane >> 4);
        int rb = wc * 16 + (lane & 15);
        short8 vbh = *(const short8*)&sB[rb * 256 + ((G ^ (rb & 7)) << 3)];
        short8 vbl = *(const short8*)&sB[8192 + rb * 256 + ((G ^ (rb & 7)) << 3)];
#pragma unroll
        for (int i = 0; i < 2; ++i) {
          int r = wr * 32 + i * 16 + (lane & 15);
          short8 av = *(const short8*)&s2[r * 256 + ((G ^ (r & 7)) << 3)];
          a3c[i] = MFMA16(av, vbh, a3c[i]);
          a3c[i] = MFMA16(av, vbl, a3c[i]);
        }
      }
#pragma unroll
      for (int i = 0; i < 2; ++i) {
        int rbase = wr * 32 + i * 16 + ((lane >> 4) << 2);
        int col = wc * 16 + (lane & 15);
#pragma unroll
        for (int rg = 0; rg < 4; ++rg) {
          int row = rbase + rg;
          c3[row * 32 + (col ^ (((row >> 2) & 7) << 2))] = a3c[i][rg];
        }
      }
    }
    __syncthreads();

    // ---- Phase E: LIF3 + mean accum (threads 0..19) ----
    if (tid < 20) {
#pragma unroll 4
      for (int u = 0; u < 64; ++u) {
        int t = t0 + u;
        if (t < 500) {
          float v = c3[u * 32 + (tid ^ (((u >> 2) & 7) << 2))];
          float r = (m3 > th3) ? th3 : 0.f;
          m3 = be3 * m3 + (v + bi3) - r;
          a3 += (m3 > th3) ? 1.f : 0.f;
        }
      }
    }
    __syncthreads();
  }
  if (tid < 20) out[(size_t)b * 20 + tid] = a3 * (1.f / 500.f);
}

extern "C" void kernel_launch(void* const* d_in, const int* in_sizes, int n_in, void* d_out,
                              int out_size, void* d_ws, size_t ws_size, hipStream_t stream) {
  const float* x = (const float*)d_in[0];
  const float* W1 = (const float*)d_in[1];
  const float* b1 = (const float*)d_in[2];
  const float* W2 = (const float*)d_in[3];
  const float* b2 = (const float*)d_in[4];
  const float* W3 = (const float*)d_in[5];
  const float* b3 = (const float*)d_in[6];
  const float* beta1 = (const float*)d_in[7];
  const float* beta2 = (const float*)d_in[8];
  const float* beta3 = (const float*)d_in[9];
  const float* thr1 = (const float*)d_in[10];
  const float* thr2 = (const float*)d_in[11];
  const float* thr3 = (const float*)d_in[12];
  float* out = (float*)d_out;

  const int M = 128000;  // B*T
  char* ws = (char*)d_ws;
  float* cur1 = (float*)ws;
  size_t off = (size_t)M * 128 * 4;
  ushort* w1h = (ushort*)(ws + off); off += 128 * 704 * 2;
  ushort* w1l = (ushort*)(ws + off); off += 128 * 704 * 2;
  ushort* w2h = (ushort*)(ws + off); off += 256 * 128 * 2;
  ushort* w2l = (ushort*)(ws + off); off += 256 * 128 * 2;
  ushort* w3h = (ushort*)(ws + off); off += 32 * 256 * 2;
  ushort* w3l = (ushort*)(ws + off); off += 32 * 256 * 2;

  split_w_kernel<<<(128 * 704 + 255) / 256, 256, 0, stream>>>(W1, w1h, w1l, 128, 700, 128, 704);
  split_w_kernel<<<(256 * 128 + 255) / 256, 256, 0, stream>>>(W2, w2h, w2l, 256, 128, 256, 128);
  split_w_kernel<<<(32 * 256 + 255) / 256, 256, 0, stream>>>(W3, w3h, w3l, 20, 256, 32, 256);

  gemm1_kernel<<<M / 128, 256, 0, stream>>>(x, w1h, w1l, cur1);
  fused_l23_kernel<<<256, 512, 0, stream>>>(cur1, b1, w2h, w2l, b2, w3h, w3l, b3,
                                            beta1, beta2, beta3, thr1, thr2, thr3, out);
}